// Round 4
// baseline (231.162 us; speedup 1.0000x reference)
//
#include <hip/hip_runtime.h>
#include <hip/hip_bf16.h>

// B=32, C=32, H=W=256, regions 4x4 of 64x64.
// Per (region p, channel c): mean/var over (B,64,64). Normalize+PReLU, then
// 3x3 conv per region (zero-padded at region borders) + bias.
// Round 4: stats pass also emits a raw bf16 copy of x (same layout) into ws;
// conv stages from the bf16 copy (half the read bytes, L3-resident).

#define EPS 1e-5f

typedef float f32x4 __attribute__((ext_vector_type(4)));
typedef __bf16 bf16x8 __attribute__((ext_vector_type(8)));
typedef short short8 __attribute__((ext_vector_type(8)));
typedef short short4v __attribute__((ext_vector_type(4)));

__device__ inline short f2bf(float f) {
  union { __hip_bfloat16 h; short s; } u;
  u.h = __float2bfloat16(f);
  return u.s;
}
__device__ inline float bf2f(unsigned short us) {
  unsigned v = (unsigned)us << 16;
  return __builtin_bit_cast(float, v);
}

// ---------------- Kernel 1: per-(b,c) plane stats + bf16 copy ----------
// 1024 blocks, one (b,c) plane (256KB) each. Fully coalesced float4 sweep;
// emits bf16 copy of x at the same linear indexing (short4 stores).
__global__ __launch_bounds__(256) void stats_partial(
    const float* __restrict__ x, float* __restrict__ ws_sum,
    float* __restrict__ ws_sq, unsigned short* __restrict__ xc) {
  int plane = blockIdx.x;            // b*32 + c
  const float* base = x + (size_t)plane * 65536;
  unsigned short* cbase = xc + (size_t)plane * 65536;
  int t = threadIdx.x;
  float s[4] = {0.f, 0.f, 0.f, 0.f}, q[4] = {0.f, 0.f, 0.f, 0.f};
#pragma unroll
  for (int R = 0; R < 4; ++R) {
#pragma unroll
    for (int ii = 0; ii < 16; ++ii) {
      int idx4 = (R * 16 + ii) * 256 + t;     // float4 index
      float4 v = *reinterpret_cast<const float4*>(base + (size_t)idx4 * 4);
      s[R] += (v.x + v.y) + (v.z + v.w);
      q[R] += (v.x * v.x + v.y * v.y) + (v.z * v.z + v.w * v.w);
      short4v c;
      c.x = f2bf(v.x); c.y = f2bf(v.y); c.z = f2bf(v.z); c.w = f2bf(v.w);
      *reinterpret_cast<short4v*>(cbase + (size_t)idx4 * 4) = c;
    }
  }
  // reduce within 16-lane groups (lanes share Cc)
#pragma unroll
  for (int R = 0; R < 4; ++R) {
#pragma unroll
    for (int off = 8; off; off >>= 1) {
      s[R] += __shfl_down(s[R], off);
      q[R] += __shfl_down(q[R], off);
    }
  }
  __shared__ float red[2][4][4][4];  // [s|q][wave][Cc][R]
  int lane = t & 63, wv = t >> 6;
  if ((lane & 15) == 0) {
    int Cc = lane >> 4;
#pragma unroll
    for (int R = 0; R < 4; ++R) {
      red[0][wv][Cc][R] = s[R];
      red[1][wv][Cc][R] = q[R];
    }
  }
  __syncthreads();
  if (t < 16) {                      // t == p
    int R = t >> 2, Cc = t & 3;
    float S = 0.f, Q = 0.f;
#pragma unroll
    for (int w = 0; w < 4; ++w) {
      S += red[0][w][Cc][R];
      Q += red[1][w][Cc][R];
    }
    ws_sum[plane * 16 + t] = S;
    ws_sq[plane * 16 + t] = Q;
  }
}

// ---------------- Kernel 2: finalize per-(p,c) scale/shift ----------------
__global__ __launch_bounds__(512) void stats_finalize(
    const float* __restrict__ ws_sum, const float* __restrict__ ws_sq,
    const float* __restrict__ gamma, const float* __restrict__ beta,
    float* __restrict__ wsA, float* __restrict__ wsB) {
  int j = threadIdx.x;               // 0..511
  int p = j >> 5, c = j & 31;
  float S = 0.f, Q = 0.f;
#pragma unroll
  for (int b = 0; b < 32; ++b) {
    int idx = (b * 32 + c) * 16 + p;
    S += ws_sum[idx];
    Q += ws_sq[idx];
  }
  const float inv = 1.0f / 131072.0f;
  float mean = S * inv;
  float var = Q * inv - mean * mean;
  float rstd = rsqrtf(var + EPS);
  float a = rstd * gamma[c];
  float bb = beta[c] - mean * a;
  wsA[p * 32 + c] = a;
  wsB[p * 32 + c] = bb;
}

// ---------------- Kernel 3: pack conv_w into MFMA A-fragments ----------------
__global__ __launch_bounds__(256) void weights_prep(
    const float* __restrict__ conv_w, unsigned short* __restrict__ wfrag) {
  int idx = blockIdx.x * 256 + threadIdx.x;
  if (idx >= 18 * 64) return;
  int lane = idx & 63;
  int th = idx >> 6;                 // t*2 + h
  int t = th >> 1, h = th & 1;
  int dy = t / 3, dx = t - dy * 3;
  int oc = h * 16 + (lane & 15);
  int ic0 = (lane >> 4) * 8;
#pragma unroll
  for (int j = 0; j < 8; ++j) {
    float w = conv_w[((oc * 32 + ic0 + j) * 3 + dy) * 3 + dx];
    wfrag[(size_t)idx * 8 + j] = (unsigned short)f2bf(w);
  }
}

// ---------------- Kernel 4: stage bf16 copy -> norm+prelu -> LDS -> MFMA ----
// block = (b, p, rt): 8 output rows x 64 cols of one region. 4 waves.
// LDS: [10 rows][66 cols][32 ic] bf16 (col 0 and 65 = zero halo).
__global__ __launch_bounds__(256) void conv_mfma(
    const unsigned short* __restrict__ xc,
    const unsigned short* __restrict__ wfrag,
    const float* __restrict__ conv_b, const float* __restrict__ prelu_a,
    const float* __restrict__ wsA, const float* __restrict__ wsB,
    float* __restrict__ out) {
  __shared__ short lds_y[10 * 66 * 32];  // 42240 B

  int blk0 = blockIdx.x;             // 4096 blocks; chunked XCD swizzle
  int blk = (blk0 & 7) * 512 + (blk0 >> 3);
  int rt = blk & 7;
  int p = (blk >> 3) & 15;
  int b = blk >> 7;
  int R = p >> 2, Cc = p & 3;
  int h0 = rt * 8;
  int tid = threadIdx.x;
  int lane = tid & 63;
  float pa = prelu_a[0];

  // per-thread-fixed staging decomposition
  int s = (tid >> 4) & 3;            // ic-slice
  int c4 = tid & 15;                 // col-quad
  int srb = tid >> 6;                // base staged-row
  int ic0 = s * 8;

  // norm coeffs for this thread's 8 channels
  float4 a0 = *reinterpret_cast<const float4*>(wsA + p * 32 + ic0);
  float4 a1 = *reinterpret_cast<const float4*>(wsA + p * 32 + ic0 + 4);
  float4 bb0 = *reinterpret_cast<const float4*>(wsB + p * 32 + ic0);
  float4 bb1 = *reinterpret_cast<const float4*>(wsB + p * 32 + ic0 + 4);
  float a_r[8] = {a0.x, a0.y, a0.z, a0.w, a1.x, a1.y, a1.z, a1.w};
  float b_r[8] = {bb0.x, bb0.y, bb0.z, bb0.w, bb1.x, bb1.y, bb1.z, bb1.w};

  // weight fragments + bias
  bf16x8 wf[18];
#pragma unroll
  for (int th = 0; th < 18; ++th) {
    short8 sv =
        *reinterpret_cast<const short8*>(wfrag + ((size_t)th * 64 + lane) * 8);
    wf[th] = __builtin_bit_cast(bf16x8, sv);
  }
  int l15 = lane & 15, l4 = lane >> 4;
  f32x4 bias0, bias1;
#pragma unroll
  for (int i = 0; i < 4; ++i) {
    bias0[i] = conv_b[l4 * 4 + i];
    bias1[i] = conv_b[16 + l4 * 4 + i];
  }

  // zero the left/right halo columns
  if (tid < 80) {
    int sr = tid >> 3;
    int rem = tid & 7;
    int colh = (rem & 1) ? 65 : 0;
    int ss = rem >> 1;
    short8 z = {0, 0, 0, 0, 0, 0, 0, 0};
    *reinterpret_cast<short8*>(&lds_y[(sr * 66 + colh) * 32 + ss * 8]) = z;
  }

  // ---- stage 10 rows x 64 cols x 32 ic from bf16 copy
#pragma unroll
  for (int it = 0; it < 3; ++it) {
    if (it < 2 || tid < 128) {
      int sr = srb + it * 4;         // staged row 0..9
      int lr = h0 - 1 + sr;          // region-local input row
      short8 packs[4];
#pragma unroll
      for (int j = 0; j < 4; ++j) packs[j] = short8{0, 0, 0, 0, 0, 0, 0, 0};
      if (lr >= 0 && lr < 64) {
        const unsigned short* xp =
            xc + (((size_t)(b * 32 + ic0) * 256 + R * 64 + lr) * 256) +
            Cc * 64 + c4 * 4;
#pragma unroll
        for (int k = 0; k < 8; ++k) {
          short4v v = *reinterpret_cast<const short4v*>(xp + (size_t)k * 65536);
          float e0 = fmaf(a_r[k], bf2f((unsigned short)v.x), b_r[k]);
          float e1 = fmaf(a_r[k], bf2f((unsigned short)v.y), b_r[k]);
          float e2 = fmaf(a_r[k], bf2f((unsigned short)v.z), b_r[k]);
          float e3 = fmaf(a_r[k], bf2f((unsigned short)v.w), b_r[k]);
          e0 = e0 > 0.f ? e0 : pa * e0;
          e1 = e1 > 0.f ? e1 : pa * e1;
          e2 = e2 > 0.f ? e2 : pa * e2;
          e3 = e3 > 0.f ? e3 : pa * e3;
          packs[0][k] = f2bf(e0);
          packs[1][k] = f2bf(e1);
          packs[2][k] = f2bf(e2);
          packs[3][k] = f2bf(e3);
        }
      }
#pragma unroll
      for (int j = 0; j < 4; ++j) {
        int col = 1 + c4 * 4 + j;
        *reinterpret_cast<short8*>(&lds_y[(sr * 66 + col) * 32 + ic0]) =
            packs[j];
      }
    }
  }
  __syncthreads();

  // ---- MFMA: each wave does 8 groups of (row r, 16-col block)
  int wv = tid >> 6;
  for (int g = 0; g < 8; ++g) {
    int gi = wv * 8 + g;
    int r = gi >> 2;
    int c0 = (gi & 3) * 16;
    f32x4 acc0 = bias0, acc1 = bias1;
#pragma unroll
    for (int t = 0; t < 9; ++t) {
      int dy = t / 3, dx = t - dy * 3;
      int sr = r + dy;
      int col = c0 + l15 + dx;
      short8 sv = *reinterpret_cast<const short8*>(
          &lds_y[(sr * 66 + col) * 32 + l4 * 8]);
      bf16x8 bv = __builtin_bit_cast(bf16x8, sv);
      acc0 = __builtin_amdgcn_mfma_f32_16x16x32_bf16(wf[t * 2], bv, acc0, 0, 0, 0);
      acc1 = __builtin_amdgcn_mfma_f32_16x16x32_bf16(wf[t * 2 + 1], bv, acc1, 0, 0, 0);
    }
    int grow = R * 64 + h0 + r;
    int gcol = Cc * 64 + c0 + l15;
    float* ob = out + (size_t)b * 32 * 65536 + (size_t)grow * 256 + gcol;
#pragma unroll
    for (int i = 0; i < 4; ++i) {
      ob[(size_t)(l4 * 4 + i) * 65536] = acc0[i];
      ob[(size_t)(16 + l4 * 4 + i) * 65536] = acc1[i];
    }
  }
}

extern "C" void kernel_launch(void* const* d_in, const int* in_sizes, int n_in,
                              void* d_out, int out_size, void* d_ws,
                              size_t ws_size, hipStream_t stream) {
  const float* x = (const float*)d_in[0];
  const float* gamma = (const float*)d_in[1];
  const float* beta = (const float*)d_in[2];
  const float* prelu_a = (const float*)d_in[3];
  const float* conv_w = (const float*)d_in[4];
  const float* conv_b = (const float*)d_in[5];
  float* out = (float*)d_out;

  float* ws = (float*)d_ws;
  float* ws_sum = ws;                          // 16384 floats
  float* ws_sq = ws + 16384;                   // 16384
  float* wsA = ws + 32768;                     // 512
  float* wsB = ws + 33280;                     // 512
  unsigned short* wfrag = (unsigned short*)(ws + 33792);   // 18*64*8 shorts
  unsigned short* xc = (unsigned short*)(ws + 40960);      // 67108864 shorts

  weights_prep<<<5, 256, 0, stream>>>(conv_w, wfrag);
  stats_partial<<<1024, 256, 0, stream>>>(x, ws_sum, ws_sq, xc);
  stats_finalize<<<1, 512, 0, stream>>>(ws_sum, ws_sq, gamma, beta, wsA, wsB);
  conv_mfma<<<4096, 256, 0, stream>>>(xc, wfrag, conv_b, prelu_a, wsA, wsB, out);
}

// Round 5
// 200.994 us; speedup vs baseline: 1.1501x; 1.1501x over previous
//
#include <hip/hip_runtime.h>
#include <hip/hip_bf16.h>

// B=32, C=32, H=W=256, regions 4x4 of 64x64.
// Per (region p, channel c): mean/var over (B,64,64). Normalize+PReLU, then
// 3x3 conv per region (zero-padded at region borders) + bias.
// Round 5: conv LDS = [10][64][32] (40960B, 4 blocks/CU), ic-slice bank
// swizzle (reads 8-way -> 2-way), edge cols via cndmask, VGPR<=128.

#define EPS 1e-5f

typedef float f32x4 __attribute__((ext_vector_type(4)));
typedef __bf16 bf16x8 __attribute__((ext_vector_type(8)));
typedef short short8 __attribute__((ext_vector_type(8)));

__device__ inline short f2bf(float f) {
  union { __hip_bfloat16 h; short s; } u;
  u.h = __float2bfloat16(f);
  return u.s;
}

// ---------------- Kernel 1: per-(b,c) plane stats, contiguous sweep ----------
__global__ __launch_bounds__(256) void stats_partial(
    const float* __restrict__ x, float* __restrict__ ws_sum,
    float* __restrict__ ws_sq) {
  int plane = blockIdx.x;            // b*32 + c
  const float* base = x + (size_t)plane * 65536;
  int t = threadIdx.x;
  float s[4] = {0.f, 0.f, 0.f, 0.f}, q[4] = {0.f, 0.f, 0.f, 0.f};
#pragma unroll
  for (int R = 0; R < 4; ++R) {
#pragma unroll
    for (int ii = 0; ii < 16; ++ii) {
      int idx4 = (R * 16 + ii) * 256 + t;     // float4 index
      float4 v = *reinterpret_cast<const float4*>(base + (size_t)idx4 * 4);
      s[R] += (v.x + v.y) + (v.z + v.w);
      q[R] += (v.x * v.x + v.y * v.y) + (v.z * v.z + v.w * v.w);
    }
  }
#pragma unroll
  for (int R = 0; R < 4; ++R) {
#pragma unroll
    for (int off = 8; off; off >>= 1) {
      s[R] += __shfl_down(s[R], off);
      q[R] += __shfl_down(q[R], off);
    }
  }
  __shared__ float red[2][4][4][4];  // [s|q][wave][Cc][R]
  int lane = t & 63, wv = t >> 6;
  if ((lane & 15) == 0) {
    int Cc = lane >> 4;
#pragma unroll
    for (int R = 0; R < 4; ++R) {
      red[0][wv][Cc][R] = s[R];
      red[1][wv][Cc][R] = q[R];
    }
  }
  __syncthreads();
  if (t < 16) {                      // t == p
    int R = t >> 2, Cc = t & 3;
    float S = 0.f, Q = 0.f;
#pragma unroll
    for (int w = 0; w < 4; ++w) {
      S += red[0][w][Cc][R];
      Q += red[1][w][Cc][R];
    }
    ws_sum[plane * 16 + t] = S;
    ws_sq[plane * 16 + t] = Q;
  }
}

// ---------------- Kernel 2: finalize per-(p,c) scale/shift ----------------
__global__ __launch_bounds__(512) void stats_finalize(
    const float* __restrict__ ws_sum, const float* __restrict__ ws_sq,
    const float* __restrict__ gamma, const float* __restrict__ beta,
    float* __restrict__ wsA, float* __restrict__ wsB) {
  int j = threadIdx.x;               // 0..511
  int p = j >> 5, c = j & 31;
  float S = 0.f, Q = 0.f;
#pragma unroll
  for (int b = 0; b < 32; ++b) {
    int idx = (b * 32 + c) * 16 + p;
    S += ws_sum[idx];
    Q += ws_sq[idx];
  }
  const float inv = 1.0f / 131072.0f;
  float mean = S * inv;
  float var = Q * inv - mean * mean;
  float rstd = rsqrtf(var + EPS);
  float a = rstd * gamma[c];
  float bb = beta[c] - mean * a;
  wsA[p * 32 + c] = a;
  wsB[p * 32 + c] = bb;
}

// ---------------- Kernel 3: pack conv_w into MFMA A-fragments ----------------
__global__ __launch_bounds__(256) void weights_prep(
    const float* __restrict__ conv_w, unsigned short* __restrict__ wfrag) {
  int idx = blockIdx.x * 256 + threadIdx.x;
  if (idx >= 18 * 64) return;
  int lane = idx & 63;
  int th = idx >> 6;                 // t*2 + h
  int t = th >> 1, h = th & 1;
  int dy = t / 3, dx = t - dy * 3;
  int oc = h * 16 + (lane & 15);
  int ic0 = (lane >> 4) * 8;
#pragma unroll
  for (int j = 0; j < 8; ++j) {
    float w = conv_w[((oc * 32 + ic0 + j) * 3 + dy) * 3 + dx];
    wfrag[(size_t)idx * 8 + j] = (unsigned short)f2bf(w);
  }
}

// ---------------- Kernel 4: normalize+prelu -> LDS bf16 -> MFMA conv ----------------
// block = (b, p, rt): 8 output rows x 64 cols of one region. 4 waves.
// LDS: [10 rows][64 cols][4 slots x 8 ic] bf16, slot swizzled by (col>>1)&3.
// Region-edge cols handled by zeroing the B-frag (uniform-guarded cndmask).
__global__ __launch_bounds__(256, 4) void conv_mfma(
    const float* __restrict__ x, const unsigned short* __restrict__ wfrag,
    const float* __restrict__ conv_b, const float* __restrict__ prelu_a,
    const float* __restrict__ wsA, const float* __restrict__ wsB,
    float* __restrict__ out) {
  __shared__ short lds_y[10 * 64 * 32];  // 40960 B -> 4 blocks/CU

  int blk0 = blockIdx.x;             // 4096 blocks; chunked XCD swizzle
  int blk = (blk0 & 7) * 512 + (blk0 >> 3);
  int rt = blk & 7;
  int p = (blk >> 3) & 15;
  int b = blk >> 7;
  int R = p >> 2, Cc = p & 3;
  int h0 = rt * 8;
  int tid = threadIdx.x;
  int lane = tid & 63;
  float pa = prelu_a[0];

  // per-thread-fixed staging decomposition
  int s = (tid >> 4) & 3;            // ic-slice
  int c4 = tid & 15;                 // col-quad
  int srb = tid >> 6;                // base staged-row
  int ic0 = s * 8;

  // norm coeffs for this thread's 8 channels
  float4 a0 = *reinterpret_cast<const float4*>(wsA + p * 32 + ic0);
  float4 a1 = *reinterpret_cast<const float4*>(wsA + p * 32 + ic0 + 4);
  float4 bb0 = *reinterpret_cast<const float4*>(wsB + p * 32 + ic0);
  float4 bb1 = *reinterpret_cast<const float4*>(wsB + p * 32 + ic0 + 4);
  float a_r[8] = {a0.x, a0.y, a0.z, a0.w, a1.x, a1.y, a1.z, a1.w};
  float b_r[8] = {bb0.x, bb0.y, bb0.z, bb0.w, bb1.x, bb1.y, bb1.z, bb1.w};

  // ---- stage 10 rows x 64 cols x 32 ic (swizzled slot = (s + col>>1) & 3)
#pragma unroll
  for (int it = 0; it < 3; ++it) {
    if (it < 2 || tid < 128) {
      int sr = srb + it * 4;         // staged row 0..9
      int lr = h0 - 1 + sr;          // region-local input row
      short8 packs[4];
#pragma unroll
      for (int j = 0; j < 4; ++j) packs[j] = short8{0, 0, 0, 0, 0, 0, 0, 0};
      if (lr >= 0 && lr < 64) {
        const float* xp =
            x + (((size_t)(b * 32 + ic0) * 256 + R * 64 + lr) * 256) +
            Cc * 64 + c4 * 4;
#pragma unroll
        for (int k = 0; k < 8; ++k) {
          float4 v = *reinterpret_cast<const float4*>(xp + (size_t)k * 65536);
          float e0 = fmaf(a_r[k], v.x, b_r[k]); e0 = e0 > 0.f ? e0 : pa * e0;
          float e1 = fmaf(a_r[k], v.y, b_r[k]); e1 = e1 > 0.f ? e1 : pa * e1;
          float e2 = fmaf(a_r[k], v.z, b_r[k]); e2 = e2 > 0.f ? e2 : pa * e2;
          float e3 = fmaf(a_r[k], v.w, b_r[k]); e3 = e3 > 0.f ? e3 : pa * e3;
          packs[0][k] = f2bf(e0);
          packs[1][k] = f2bf(e1);
          packs[2][k] = f2bf(e2);
          packs[3][k] = f2bf(e3);
        }
      }
#pragma unroll
      for (int j = 0; j < 4; ++j) {
        int col = c4 * 4 + j;        // 0..63, no halo offset
        int slot = (s + (col >> 1)) & 3;
        *reinterpret_cast<short8*>(&lds_y[(sr * 64 + col) * 32 + slot * 8]) =
            packs[j];
      }
    }
  }
  __syncthreads();

  // ---- weight fragments + bias (post-barrier: lower VGPR during staging)
  bf16x8 wf[18];
#pragma unroll
  for (int th = 0; th < 18; ++th) {
    short8 sv =
        *reinterpret_cast<const short8*>(wfrag + ((size_t)th * 64 + lane) * 8);
    wf[th] = __builtin_bit_cast(bf16x8, sv);
  }
  int l15 = lane & 15, l4 = lane >> 4;
  f32x4 bias0, bias1;
#pragma unroll
  for (int i = 0; i < 4; ++i) {
    bias0[i] = conv_b[l4 * 4 + i];
    bias1[i] = conv_b[16 + l4 * 4 + i];
  }

  // ---- MFMA: each wave does 8 groups of (row r, 16-col block)
  int wv = tid >> 6;
  const short8 z8 = {0, 0, 0, 0, 0, 0, 0, 0};
  for (int g = 0; g < 8; ++g) {
    int gi = wv * 8 + g;
    int r = gi >> 2;
    int c0 = (gi & 3) * 16;
    f32x4 acc0 = bias0, acc1 = bias1;
#pragma unroll
    for (int t9 = 0; t9 < 9; ++t9) {
      const int dy = t9 / 3, dx = t9 - dy * 3;
      int sr = r + dy;
      int col_in = c0 + l15 + dx - 1;     // -1..64 possible at edges
      int colc = col_in & 63;
      int slot = (l4 + (colc >> 1)) & 3;
      short8 sv = *reinterpret_cast<const short8*>(
          &lds_y[(sr * 64 + colc) * 32 + slot * 8]);
      if (dx == 0) {
        if (c0 == 0 && l15 == 0) sv = z8;     // col -1 -> zero pad
      }
      if (dx == 2) {
        if (c0 == 48 && l15 == 15) sv = z8;   // col 64 -> zero pad
      }
      bf16x8 bv = __builtin_bit_cast(bf16x8, sv);
      acc0 = __builtin_amdgcn_mfma_f32_16x16x32_bf16(wf[t9 * 2], bv, acc0, 0, 0, 0);
      acc1 = __builtin_amdgcn_mfma_f32_16x16x32_bf16(wf[t9 * 2 + 1], bv, acc1, 0, 0, 0);
    }
    int grow = R * 64 + h0 + r;
    int gcol = Cc * 64 + c0 + l15;
    float* ob = out + (size_t)b * 32 * 65536 + (size_t)grow * 256 + gcol;
#pragma unroll
    for (int i = 0; i < 4; ++i) {
      ob[(size_t)(l4 * 4 + i) * 65536] = acc0[i];
      ob[(size_t)(16 + l4 * 4 + i) * 65536] = acc1[i];
    }
  }
}

extern "C" void kernel_launch(void* const* d_in, const int* in_sizes, int n_in,
                              void* d_out, int out_size, void* d_ws,
                              size_t ws_size, hipStream_t stream) {
  const float* x = (const float*)d_in[0];
  const float* gamma = (const float*)d_in[1];
  const float* beta = (const float*)d_in[2];
  const float* prelu_a = (const float*)d_in[3];
  const float* conv_w = (const float*)d_in[4];
  const float* conv_b = (const float*)d_in[5];
  float* out = (float*)d_out;

  float* ws = (float*)d_ws;
  float* ws_sum = ws;                          // 16384 floats
  float* ws_sq = ws + 16384;                   // 16384
  float* wsA = ws + 32768;                     // 512
  float* wsB = ws + 33280;                     // 512
  unsigned short* wfrag = (unsigned short*)(ws + 33792);   // 18*64*8 shorts

  weights_prep<<<5, 256, 0, stream>>>(conv_w, wfrag);
  stats_partial<<<1024, 256, 0, stream>>>(x, ws_sum, ws_sq);
  stats_finalize<<<1, 512, 0, stream>>>(ws_sum, ws_sq, gamma, beta, wsA, wsB);
  conv_mfma<<<4096, 256, 0, stream>>>(x, wfrag, conv_b, prelu_a, wsA, wsB, out);
}